// Round 8
// baseline (260.699 us; speedup 1.0000x reference)
//
#include <hip/hip_runtime.h>
#include <stdint.h>

typedef unsigned short u16;
typedef __attribute__((ext_vector_type(8))) unsigned short ushort8;
typedef __attribute__((ext_vector_type(4))) unsigned short ushort4v;
typedef __attribute__((ext_vector_type(8))) __bf16 bf16x8;
typedef __attribute__((ext_vector_type(16))) float f32x16;

__device__ __forceinline__ u16 f2bf(float f) {
    union { float f; unsigned int u; } v; v.f = f;
    unsigned int r = v.u + 0x7FFFu + ((v.u >> 16) & 1u);   // RNE
    return (u16)(r >> 16);
}
__device__ __forceinline__ float bf2f(u16 b) {
    union { unsigned int u; float f; } v; v.u = ((unsigned int)b) << 16;
    return v.f;
}

typedef __attribute__((address_space(1))) const uint32_t* gptr_t;
typedef __attribute__((address_space(3))) uint32_t* lptr_t;
__device__ __forceinline__ void async_copy16(const void* g, void* l) {
    __builtin_amdgcn_global_load_lds((gptr_t)g, (lptr_t)l, 16, 0, 0);
}

// ---------------- merged pre-pass: x->bf16, sign(W1)->bf16, W4 -> W4T ----------------

__global__ __launch_bounds__(256) void pre_kernel(
    const float* __restrict__ x, const float* __restrict__ W1,
    const float* __restrict__ W4,
    u16* __restrict__ Xb, u16* __restrict__ W1b, u16* __restrict__ W4T)
{
    const int b = blockIdx.x;
    if (b < 12288) {
        int i = b * 256 + threadIdx.x;
        const float4* p = (const float4*)(x + (size_t)i * 8);
        float4 x0 = p[0], x1 = p[1];
        ushort8 o;
        o[0] = f2bf(x0.x); o[1] = f2bf(x0.y); o[2] = f2bf(x0.z); o[3] = f2bf(x0.w);
        o[4] = f2bf(x1.x); o[5] = f2bf(x1.y); o[6] = f2bf(x1.z); o[7] = f2bf(x1.w);
        *(ushort8*)(Xb + (size_t)i * 8) = o;
    } else if (b < 13824) {
        int i = (b - 12288) * 256 + threadIdx.x;
        const float4* p = (const float4*)(W1 + (size_t)i * 8);
        float4 x0 = p[0], x1 = p[1];
        ushort8 o;
        o[0] = x0.x >= 0.f ? 0x3F80 : 0xBF80;
        o[1] = x0.y >= 0.f ? 0x3F80 : 0xBF80;
        o[2] = x0.z >= 0.f ? 0x3F80 : 0xBF80;
        o[3] = x0.w >= 0.f ? 0x3F80 : 0xBF80;
        o[4] = x1.x >= 0.f ? 0x3F80 : 0xBF80;
        o[5] = x1.y >= 0.f ? 0x3F80 : 0xBF80;
        o[6] = x1.z >= 0.f ? 0x3F80 : 0xBF80;
        o[7] = x1.w >= 0.f ? 0x3F80 : 0xBF80;
        *(ushort8*)(W1b + (size_t)i * 8) = o;
    } else {
        int idx = (b - 13824) * 256 + threadIdx.x;
        int k = idx >> 4, c = idx & 15;
        u16 v = 0;
        if (c < 10) v = (W4[(size_t)c * 1024 + k] >= 0.f) ? 0x3F80 : 0xBF80;
        W4T[idx] = v;
    }
}

// W' = bf16(sign(W)*sc_k), bias_n = sum_k sign(W)*sh_k.
__global__ __launch_bounds__(256) void rescale_w(
    const float* __restrict__ W, const float* __restrict__ ss,
    u16* __restrict__ Wp, float* __restrict__ bias)
{
    const int lane = threadIdx.x & 63;
    const int wid  = threadIdx.x >> 6;
    const int r    = blockIdx.x * 4 + wid;
    float bsum = 0.f;
    #pragma unroll
    for (int k0 = 0; k0 < 1024; k0 += 256) {
        int k = k0 + lane * 4;
        float4 w  = *(const float4*)(W + (size_t)r * 1024 + k);
        float4 sc = *(const float4*)(ss + k);
        float4 sh = *(const float4*)(ss + 1024 + k);
        ushort4v o;
        o[0] = f2bf(w.x >= 0.f ? sc.x : -sc.x);
        o[1] = f2bf(w.y >= 0.f ? sc.y : -sc.y);
        o[2] = f2bf(w.z >= 0.f ? sc.z : -sc.z);
        o[3] = f2bf(w.w >= 0.f ? sc.w : -sc.w);
        bsum += (w.x >= 0.f ? sh.x : -sh.x) + (w.y >= 0.f ? sh.y : -sh.y)
              + (w.z >= 0.f ? sh.z : -sh.z) + (w.w >= 0.f ? sh.w : -sh.w);
        *(ushort4v*)(Wp + (size_t)r * 1024 + k) = o;
    }
    #pragma unroll
    for (int off = 32; off; off >>= 1) bsum += __shfl_xor(bsum, off, 64);
    if (lane == 0) bias[r] = bsum;
}

// XCD-aware bijective swizzle for grid (64,8)
__device__ __forceinline__ void xcd_map(int& mm, int& jj) {
    const int d = blockIdx.x + blockIdx.y * gridDim.x;
    mm = (d & 7) + (d >> 6) * 8;
    jj = (d >> 3) & 7;
}

// ---------------- GEMM (bf16, 32x32x16 MFMA, reg-prefetch pipeline) ----------------
// H = bf16(relu(A @ B^T [+ bias])), fused BN column stats.
// 128x128 tile, BK=64, 4 waves (64x64), dbuf LDS via global_load_lds.
// Swizzle: LDS (row r, 16B-slot s) holds k-block s ^ rho(r), rho(r)=(r&7)^((r>>3)&7),
// applied on BOTH the pre-swizzled global source and the ds_read slot.
// Pipeline: frags(t+1) read between MFMA halves of frags(t); counted vmcnt.

__global__ __launch_bounds__(256) void gemm_fused(
    const u16* __restrict__ A, const u16* __restrict__ B,
    u16* __restrict__ H, const float* __restrict__ bias,
    float* __restrict__ partS, float* __restrict__ partS2,
    int M, int N, int K)
{
    __shared__ __align__(16) u16 As[2][128 * 64];
    __shared__ __align__(16) u16 Bs[2][128 * 64];

    const int tid  = threadIdx.x;
    const int wid  = tid >> 6;
    const int lane = tid & 63;
    const int cl   = lane & 31;
    const int hi   = lane >> 5;
    const int wr   = wid >> 1;
    const int wc   = wid & 1;

    int mm, jj;
    xcd_map(mm, jj);
    const int row0 = mm * 128;
    const int col0 = jj * 128;

    // staging: linear LDS dest; global source col pre-swizzled with rho(row)
    const int s_r = tid >> 3;
    const int c8b = (tid & 7) ^ (s_r & 7) ^ (s_r >> 3);
    const u16* gA = A + (size_t)(row0 + s_r) * K;
    const u16* gB = B + (size_t)(col0 + s_r) * K;

    // fragment read bases/slots: rho0 = (cl&7)^(cl>>3); block i=1 flips bit2 of rho
    const int a_base0 = (wr * 64 +  0 + cl) * 64;
    const int a_base1 = (wr * 64 + 32 + cl) * 64;
    const int b_base0 = (wc * 64 +  0 + cl) * 64;
    const int b_base1 = (wc * 64 + 32 + cl) * 64;
    const int rho0 = (cl & 7) ^ (cl >> 3);
    int xk0[4], xk1[4];
    #pragma unroll
    for (int kt = 0; kt < 4; ++kt) {
        xk0[kt] = ((((kt << 1) | hi) ^ rho0) << 3);
        xk1[kt] = xk0[kt] ^ 32;   // rho ^= 4  -> byte slot ^= 4*8
    }

    f32x16 acc00, acc01, acc10, acc11;
    #pragma unroll
    for (int r = 0; r < 16; ++r) { acc00[r]=0.f; acc01[r]=0.f; acc10[r]=0.f; acc11[r]=0.f; }

    const int NT = K >> 6;

    auto STAGE = [&](int buf, int t) {
        #pragma unroll
        for (int i = 0; i < 4; ++i) {
            const int co = (c8b ^ ((i & 1) << 2)) << 3;
            async_copy16(gA + ((size_t)i * 32) * K + (size_t)t * 64 + co,
                         &As[buf][i * 2048 + wid * 512]);
        }
        #pragma unroll
        for (int i = 0; i < 4; ++i) {
            const int co = (c8b ^ ((i & 1) << 2)) << 3;
            async_copy16(gB + ((size_t)i * 32) * K + (size_t)t * 64 + co,
                         &Bs[buf][i * 2048 + wid * 512]);
        }
    };

    // two named fragment sets (rule #20: static indexing only)
    bf16x8 pa0[4], pa1[4], pb0[4], pb1[4];
    bf16x8 qa0[4], qa1[4], qb0[4], qb1[4];

#define READ_P(buf)                                                   \
    _Pragma("unroll")                                                 \
    for (int kt = 0; kt < 4; ++kt) {                                  \
        pa0[kt] = *(const bf16x8*)&As[buf][a_base0 + xk0[kt]];        \
        pa1[kt] = *(const bf16x8*)&As[buf][a_base1 + xk1[kt]];        \
        pb0[kt] = *(const bf16x8*)&Bs[buf][b_base0 + xk0[kt]];        \
        pb1[kt] = *(const bf16x8*)&Bs[buf][b_base1 + xk1[kt]];        \
    }
#define READ_Q(buf)                                                   \
    _Pragma("unroll")                                                 \
    for (int kt = 0; kt < 4; ++kt) {                                  \
        qa0[kt] = *(const bf16x8*)&As[buf][a_base0 + xk0[kt]];        \
        qa1[kt] = *(const bf16x8*)&As[buf][a_base1 + xk1[kt]];        \
        qb0[kt] = *(const bf16x8*)&Bs[buf][b_base0 + xk0[kt]];        \
        qb1[kt] = *(const bf16x8*)&Bs[buf][b_base1 + xk1[kt]];        \
    }
#define MFMA4(SA0, SA1, SB0, SB1, kt)                                                      \
    acc00 = __builtin_amdgcn_mfma_f32_32x32x16_bf16(SA0[kt], SB0[kt], acc00, 0, 0, 0);     \
    acc01 = __builtin_amdgcn_mfma_f32_32x32x16_bf16(SA0[kt], SB1[kt], acc01, 0, 0, 0);     \
    acc10 = __builtin_amdgcn_mfma_f32_32x32x16_bf16(SA1[kt], SB0[kt], acc10, 0, 0, 0);     \
    acc11 = __builtin_amdgcn_mfma_f32_32x32x16_bf16(SA1[kt], SB1[kt], acc11, 0, 0, 0);

    // prologue: tiles 0,1 staged; frags(0) -> P
    STAGE(0, 0);
    STAGE(1, 1);
    asm volatile("s_waitcnt vmcnt(8)" ::: "memory");
    __builtin_amdgcn_s_barrier();
    READ_P(0)
    asm volatile("s_waitcnt lgkmcnt(0)" ::: "memory");
    __builtin_amdgcn_sched_barrier(0);
    __builtin_amdgcn_s_barrier();

#define G_ITER(T, MA0, MA1, MB0, MB1, READ_N)                                 \
    {                                                                         \
        const int bufc = (T) & 1;                                             \
        if ((T) + 2 < NT) STAGE(bufc, (T) + 2);                               \
        __builtin_amdgcn_s_setprio(1);                                        \
        MFMA4(MA0, MA1, MB0, MB1, 0)                                          \
        MFMA4(MA0, MA1, MB0, MB1, 1)                                          \
        __builtin_amdgcn_s_setprio(0);                                        \
        if ((T) + 1 < NT) {                                                   \
            if ((T) + 2 < NT) asm volatile("s_waitcnt vmcnt(8)" ::: "memory");\
            else              asm volatile("s_waitcnt vmcnt(0)" ::: "memory");\
            __builtin_amdgcn_s_barrier();                                     \
            READ_N(((T) + 1) & 1)                                             \
        }                                                                     \
        __builtin_amdgcn_s_setprio(1);                                        \
        MFMA4(MA0, MA1, MB0, MB1, 2)                                          \
        MFMA4(MA0, MA1, MB0, MB1, 3)                                          \
        __builtin_amdgcn_s_setprio(0);                                        \
        if ((T) + 1 < NT) {                                                   \
            asm volatile("s_waitcnt lgkmcnt(0)" ::: "memory");                \
            __builtin_amdgcn_sched_barrier(0);                                \
            __builtin_amdgcn_s_barrier();                                     \
        }                                                                     \
    }

    for (int t2 = 0; t2 < NT; t2 += 2) {
        G_ITER(t2,     pa0, pa1, pb0, pb1, READ_Q)   // MFMA P=frags(t2), read frags(t2+1)->Q
        G_ITER(t2 + 1, qa0, qa1, qb0, qb1, READ_P)   // MFMA Q,            read frags(t2+2)->P
    }
#undef G_ITER
#undef MFMA4
#undef READ_P
#undef READ_Q

    // epilogue: D col=lane&31, row=(reg&3)+8*(reg>>2)+4*hi  (measured m74/m101)
    #pragma unroll
    for (int j = 0; j < 2; ++j) {
        const int c = col0 + wc * 64 + j * 32 + cl;
        const float bj = bias ? bias[c] : 0.f;
        float s = 0.f, s2 = 0.f;
        #pragma unroll
        for (int i = 0; i < 2; ++i) {
            #pragma unroll
            for (int reg = 0; reg < 16; ++reg) {
                const int rl = (reg & 3) + 8 * (reg >> 2) + 4 * hi;
                const int r = row0 + wr * 64 + i * 32 + rl;
                float x = (i == 0 ? (j == 0 ? acc00[reg] : acc01[reg])
                                  : (j == 0 ? acc10[reg] : acc11[reg])) + bj;
                x = x > 0.f ? x : 0.f;
                s += x; s2 += x * x;
                H[(size_t)r * N + c] = f2bf(x);
            }
        }
        s  += __shfl_xor(s, 32, 64);
        s2 += __shfl_xor(s2, 32, 64);
        if (hi == 0) {
            const int p = mm * 2 + wr;
            partS [(size_t)p * 1024 + c] = s;
            partS2[(size_t)p * 1024 + c] = s2;
        }
    }
}

// ---------------- BN finalize ----------------

__global__ __launch_bounds__(256) void bn_finalize(
    const float* __restrict__ partS, const float* __restrict__ partS2,
    const float* __restrict__ gamma, const float* __restrict__ beta,
    float* __restrict__ ss)
{
    int c = blockIdx.x * 256 + threadIdx.x;
    float s = 0.f, s2 = 0.f;
    for (int i = 0; i < 128; ++i) {
        s  += partS [(size_t)i * 1024 + c];
        s2 += partS2[(size_t)i * 1024 + c];
    }
    float mean = s * (1.0f / 8192.0f);
    float var  = fmaxf(s2 * (1.0f / 8192.0f) - mean * mean, 0.f);
    float sc   = gamma[c] * rsqrtf(var + 1e-5f);
    ss[c]        = sc;
    ss[1024 + c] = beta[c] - mean * sc;
}

// ---------------- head: out[8192,10] = BN3(H) @ W4T (K=1024) ----------------

__global__ __launch_bounds__(256) void head_kernel(
    const u16* __restrict__ H, const u16* __restrict__ W4T,
    const float* __restrict__ ss, float* __restrict__ out)
{
    const int lane = threadIdx.x & 63;
    const int wid  = threadIdx.x >> 6;
    const int r    = blockIdx.x * 4 + wid;

    float acc[10];
    #pragma unroll
    for (int c = 0; c < 10; c++) acc[c] = 0.f;

    #pragma unroll
    for (int j = 0; j < 16; ++j) {
        int k = j * 64 + lane;
        float a = fmaf(bf2f(H[(size_t)r * 1024 + k]), ss[k], ss[1024 + k]);
        ushort8 w0 = *(const ushort8*)(W4T + (size_t)k * 16);
        acc[0] += a * bf2f(w0[0]); acc[1] += a * bf2f(w0[1]);
        acc[2] += a * bf2f(w0[2]); acc[3] += a * bf2f(w0[3]);
        acc[4] += a * bf2f(w0[4]); acc[5] += a * bf2f(w0[5]);
        acc[6] += a * bf2f(w0[6]); acc[7] += a * bf2f(w0[7]);
        u16 w8 = W4T[(size_t)k * 16 + 8];
        u16 w9 = W4T[(size_t)k * 16 + 9];
        acc[8] += a * bf2f(w8);    acc[9] += a * bf2f(w9);
    }
    #pragma unroll
    for (int c = 0; c < 10; c++) {
        float s = acc[c];
        #pragma unroll
        for (int off = 32; off > 0; off >>= 1) s += __shfl_xor(s, off, 64);
        acc[c] = s;
    }
    if (lane == 0) {
        #pragma unroll
        for (int c = 0; c < 10; c++) out[(size_t)r * 10 + c] = acc[c];
    }
}

// ---------------- launch ----------------

extern "C" void kernel_launch(void* const* d_in, const int* in_sizes, int n_in,
                              void* d_out, int out_size, void* d_ws, size_t ws_size,
                              hipStream_t stream) {
    const float* x  = (const float*)d_in[0];
    const float* W1 = (const float*)d_in[1];
    const float* W2 = (const float*)d_in[2];
    const float* W3 = (const float*)d_in[3];
    const float* W4 = (const float*)d_in[4];
    const float* g1 = (const float*)d_in[5];
    const float* b1 = (const float*)d_in[6];
    const float* g2 = (const float*)d_in[7];
    const float* b2 = (const float*)d_in[8];
    const float* g3 = (const float*)d_in[9];
    const float* b3 = (const float*)d_in[10];
    float* out = (float*)d_out;

    char* ws = (char*)d_ws;
    u16*   Xb     = (u16*)  (ws + 0);           // 50,331,648 (x bf16)
    u16*   Hb0    = (u16*)  (ws + 50331648);    // 16,777,216
    u16*   Hb1    = (u16*)  (ws + 67108864);    // 16,777,216
    u16*   W1b    = (u16*)  (ws + 83886080);    //  6,291,456
    u16*   W2p    = (u16*)  (ws + 90177536);    //  2,097,152
    u16*   W3p    = (u16*)  (ws + 92274688);    //  2,097,152
    u16*   W4T    = (u16*)  (ws + 94371840);    //     32,768
    float* partS  = (float*)(ws + 94404608);    //    524,288
    float* partS2 = (float*)(ws + 94928896);    //    524,288
    float* ss     = (float*)(ws + 95453184);    //      8,192
    float* bias2  = (float*)(ws + 95461376);    //      4,096
    float* bias3  = (float*)(ws + 95465472);    //      4,096

    pre_kernel<<<13888, 256, 0, stream>>>(x, W1, W4, Xb, W1b, W4T);

    dim3 gemm_grid(64, 8);   // M/128, N/128

    // layer 1 (bf16 x, no bias)
    gemm_fused<<<gemm_grid, 256, 0, stream>>>(Xb, W1b, Hb0, nullptr, partS, partS2, 8192, 1024, 3072);
    bn_finalize<<<4, 256, 0, stream>>>(partS, partS2, g1, b1, ss);
    rescale_w<<<256, 256, 0, stream>>>(W2, ss, W2p, bias2);

    // layer 2
    gemm_fused<<<gemm_grid, 256, 0, stream>>>(Hb0, W2p, Hb1, bias2, partS, partS2, 8192, 1024, 1024);
    bn_finalize<<<4, 256, 0, stream>>>(partS, partS2, g2, b2, ss);
    rescale_w<<<256, 256, 0, stream>>>(W3, ss, W3p, bias3);

    // layer 3
    gemm_fused<<<gemm_grid, 256, 0, stream>>>(Hb1, W3p, Hb0, bias3, partS, partS2, 8192, 1024, 1024);
    bn_finalize<<<4, 256, 0, stream>>>(partS, partS2, g3, b3, ss);

    // head (BN3 applied on the fly)
    head_kernel<<<2048, 256, 0, stream>>>(Hb0, W4T, ss, out);
}

// Round 9
// 192.598 us; speedup vs baseline: 1.3536x; 1.3536x over previous
//
#include <hip/hip_runtime.h>
#include <stdint.h>

typedef unsigned short u16;
typedef __attribute__((ext_vector_type(8))) unsigned short ushort8;
typedef __attribute__((ext_vector_type(4))) unsigned short ushort4v;
typedef __attribute__((ext_vector_type(8))) __bf16 bf16x8;
typedef __attribute__((ext_vector_type(16))) float f32x16;

__device__ __forceinline__ u16 f2bf(float f) {
    union { float f; unsigned int u; } v; v.f = f;
    unsigned int r = v.u + 0x7FFFu + ((v.u >> 16) & 1u);   // RNE
    return (u16)(r >> 16);
}
__device__ __forceinline__ float bf2f(u16 b) {
    union { unsigned int u; float f; } v; v.u = ((unsigned int)b) << 16;
    return v.f;
}

typedef __attribute__((address_space(1))) const uint32_t* gptr_t;
typedef __attribute__((address_space(3))) uint32_t* lptr_t;
__device__ __forceinline__ void async_copy16(const void* g, void* l) {
    __builtin_amdgcn_global_load_lds((gptr_t)g, (lptr_t)l, 16, 0, 0);
}

// ---------------- merged pre-pass: x->bf16, sign(W1)->bf16, W4 -> W4T ----------------

__global__ __launch_bounds__(256) void pre_kernel(
    const float* __restrict__ x, const float* __restrict__ W1,
    const float* __restrict__ W4,
    u16* __restrict__ Xb, u16* __restrict__ W1b, u16* __restrict__ W4T)
{
    const int b = blockIdx.x;
    if (b < 12288) {
        int i = b * 256 + threadIdx.x;
        const float4* p = (const float4*)(x + (size_t)i * 8);
        float4 x0 = p[0], x1 = p[1];
        ushort8 o;
        o[0] = f2bf(x0.x); o[1] = f2bf(x0.y); o[2] = f2bf(x0.z); o[3] = f2bf(x0.w);
        o[4] = f2bf(x1.x); o[5] = f2bf(x1.y); o[6] = f2bf(x1.z); o[7] = f2bf(x1.w);
        *(ushort8*)(Xb + (size_t)i * 8) = o;
    } else if (b < 13824) {
        int i = (b - 12288) * 256 + threadIdx.x;
        const float4* p = (const float4*)(W1 + (size_t)i * 8);
        float4 x0 = p[0], x1 = p[1];
        ushort8 o;
        o[0] = x0.x >= 0.f ? 0x3F80 : 0xBF80;
        o[1] = x0.y >= 0.f ? 0x3F80 : 0xBF80;
        o[2] = x0.z >= 0.f ? 0x3F80 : 0xBF80;
        o[3] = x0.w >= 0.f ? 0x3F80 : 0xBF80;
        o[4] = x1.x >= 0.f ? 0x3F80 : 0xBF80;
        o[5] = x1.y >= 0.f ? 0x3F80 : 0xBF80;
        o[6] = x1.z >= 0.f ? 0x3F80 : 0xBF80;
        o[7] = x1.w >= 0.f ? 0x3F80 : 0xBF80;
        *(ushort8*)(W1b + (size_t)i * 8) = o;
    } else {
        int idx = (b - 13824) * 256 + threadIdx.x;
        int k = idx >> 4, c = idx & 15;
        u16 v = 0;
        if (c < 10) v = (W4[(size_t)c * 1024 + k] >= 0.f) ? 0x3F80 : 0xBF80;
        W4T[idx] = v;
    }
}

// W' = bf16(sign(W)*sc_k), bias_n = sum_k sign(W)*sh_k.
__global__ __launch_bounds__(256) void rescale_w(
    const float* __restrict__ W, const float* __restrict__ ss,
    u16* __restrict__ Wp, float* __restrict__ bias)
{
    const int lane = threadIdx.x & 63;
    const int wid  = threadIdx.x >> 6;
    const int r    = blockIdx.x * 4 + wid;
    float bsum = 0.f;
    #pragma unroll
    for (int k0 = 0; k0 < 1024; k0 += 256) {
        int k = k0 + lane * 4;
        float4 w  = *(const float4*)(W + (size_t)r * 1024 + k);
        float4 sc = *(const float4*)(ss + k);
        float4 sh = *(const float4*)(ss + 1024 + k);
        ushort4v o;
        o[0] = f2bf(w.x >= 0.f ? sc.x : -sc.x);
        o[1] = f2bf(w.y >= 0.f ? sc.y : -sc.y);
        o[2] = f2bf(w.z >= 0.f ? sc.z : -sc.z);
        o[3] = f2bf(w.w >= 0.f ? sc.w : -sc.w);
        bsum += (w.x >= 0.f ? sh.x : -sh.x) + (w.y >= 0.f ? sh.y : -sh.y)
              + (w.z >= 0.f ? sh.z : -sh.z) + (w.w >= 0.f ? sh.w : -sh.w);
        *(ushort4v*)(Wp + (size_t)r * 1024 + k) = o;
    }
    #pragma unroll
    for (int off = 32; off; off >>= 1) bsum += __shfl_xor(bsum, off, 64);
    if (lane == 0) bias[r] = bsum;
}

// XCD-aware bijective swizzle for grid (64,8)
__device__ __forceinline__ void xcd_map(int& mm, int& jj) {
    const int d = blockIdx.x + blockIdx.y * gridDim.x;
    mm = (d & 7) + (d >> 6) * 8;
    jj = (d >> 3) & 7;
}

// ---------------- GEMM (bf16, 32x32x16 MFMA): H = bf16(relu(A @ B^T [+ bias])), fused BN stats --
// Round-7 schedule (proven fastest) + round-8 dual-rho conflict-free swizzle (proven 0 conflicts).
// rho(row) = (row&7) ^ ((row>>3)&7), applied on pre-swizzled global source AND ds_read slot.

__global__ __launch_bounds__(256) void gemm_fused(
    const u16* __restrict__ A, const u16* __restrict__ B,
    u16* __restrict__ H, const float* __restrict__ bias,
    float* __restrict__ partS, float* __restrict__ partS2,
    int M, int N, int K)
{
    __shared__ __align__(16) u16 As[2][128 * 64];
    __shared__ __align__(16) u16 Bs[2][128 * 64];

    const int tid  = threadIdx.x;
    const int wid  = tid >> 6;
    const int lane = tid & 63;
    const int cl   = lane & 31;        // row within 32 (A) / col within 32 (B/D)
    const int hi   = lane >> 5;        // k-half
    const int wr   = wid >> 1;
    const int wc   = wid & 1;

    int mm, jj;
    xcd_map(mm, jj);
    const int row0 = mm * 128;
    const int col0 = jj * 128;

    // staging: linear LDS dest; global source slot pre-swizzled with rho(row)
    const int s_r = tid >> 3;
    const int c8b = (tid & 7) ^ (s_r & 7) ^ (s_r >> 3);
    const u16* gA = A + (size_t)(row0 + s_r) * K;
    const u16* gB = B + (size_t)(col0 + s_r) * K;

    // fragment read bases/slots: rho0 = (cl&7)^(cl>>3); row-block i=1 (rows+32) flips bit2
    const int a_base0 = (wr * 64 +  0 + cl) * 64;
    const int a_base1 = (wr * 64 + 32 + cl) * 64;
    const int b_base0 = (wc * 64 +  0 + cl) * 64;
    const int b_base1 = (wc * 64 + 32 + cl) * 64;
    const int rho0 = (cl & 7) ^ (cl >> 3);
    int xk0[4], xk1[4];
    #pragma unroll
    for (int kt = 0; kt < 4; ++kt) {
        xk0[kt] = ((((kt << 1) | hi) ^ rho0) << 3);
        xk1[kt] = xk0[kt] ^ 32;   // rho ^= 4 -> byte slot ^= 32
    }

    f32x16 acc[2][2];
    #pragma unroll
    for (int i = 0; i < 2; ++i)
        #pragma unroll
        for (int j = 0; j < 2; ++j)
            #pragma unroll
            for (int r = 0; r < 16; ++r)
                acc[i][j][r] = 0.f;

    const int NT = K >> 6;

    auto STAGE = [&](int buf, int t) {
        #pragma unroll
        for (int i = 0; i < 4; ++i) {
            const int co = (c8b ^ ((i & 1) << 2)) << 3;   // rho(i*32+s_r) source slot
            async_copy16(gA + ((size_t)i * 32) * K + (size_t)t * 64 + co,
                         &As[buf][i * 2048 + wid * 512]);
        }
        #pragma unroll
        for (int i = 0; i < 4; ++i) {
            const int co = (c8b ^ ((i & 1) << 2)) << 3;
            async_copy16(gB + ((size_t)i * 32) * K + (size_t)t * 64 + co,
                         &Bs[buf][i * 2048 + wid * 512]);
        }
    };

    STAGE(0, 0);
    STAGE(1, 1);

    for (int t = 0; t < NT; ++t) {
        const int buf = t & 1;
        if (t + 1 < NT) asm volatile("s_waitcnt vmcnt(8)" ::: "memory");
        else            asm volatile("s_waitcnt vmcnt(0)" ::: "memory");
        __builtin_amdgcn_s_barrier();

        // issue 16 ds_reads in kt-group order (pinned so lgkm counts are meaningful)
        bf16x8 af0[4], af1[4], bg0[4], bg1[4];
        #pragma unroll
        for (int kt = 0; kt < 4; ++kt) {
            af0[kt] = *(const bf16x8*)&As[buf][a_base0 + xk0[kt]];
            af1[kt] = *(const bf16x8*)&As[buf][a_base1 + xk1[kt]];
            bg0[kt] = *(const bf16x8*)&Bs[buf][b_base0 + xk0[kt]];
            bg1[kt] = *(const bf16x8*)&Bs[buf][b_base1 + xk1[kt]];
            __builtin_amdgcn_sched_barrier(0);
        }

        asm volatile("s_waitcnt lgkmcnt(12)" ::: "memory");   // kt0 frags ready
        __builtin_amdgcn_sched_barrier(0);
        __builtin_amdgcn_s_setprio(1);
        acc[0][0] = __builtin_amdgcn_mfma_f32_32x32x16_bf16(af0[0], bg0[0], acc[0][0], 0, 0, 0);
        acc[0][1] = __builtin_amdgcn_mfma_f32_32x32x16_bf16(af0[0], bg1[0], acc[0][1], 0, 0, 0);
        acc[1][0] = __builtin_amdgcn_mfma_f32_32x32x16_bf16(af1[0], bg0[0], acc[1][0], 0, 0, 0);
        acc[1][1] = __builtin_amdgcn_mfma_f32_32x32x16_bf16(af1[0], bg1[0], acc[1][1], 0, 0, 0);
        asm volatile("s_waitcnt lgkmcnt(8)" ::: "memory");    // kt1 frags ready
        __builtin_amdgcn_sched_barrier(0);
        acc[0][0] = __builtin_amdgcn_mfma_f32_32x32x16_bf16(af0[1], bg0[1], acc[0][0], 0, 0, 0);
        acc[0][1] = __builtin_amdgcn_mfma_f32_32x32x16_bf16(af0[1], bg1[1], acc[0][1], 0, 0, 0);
        acc[1][0] = __builtin_amdgcn_mfma_f32_32x32x16_bf16(af1[1], bg0[1], acc[1][0], 0, 0, 0);
        acc[1][1] = __builtin_amdgcn_mfma_f32_32x32x16_bf16(af1[1], bg1[1], acc[1][1], 0, 0, 0);
        __builtin_amdgcn_s_setprio(0);

        asm volatile("s_waitcnt lgkmcnt(0)" ::: "memory");    // all reads drained
        __builtin_amdgcn_sched_barrier(0);
        __builtin_amdgcn_s_barrier();                         // buf free for overwrite

        if (t + 2 < NT) STAGE(buf, t + 2);                    // overlaps kt2/kt3 MFMA

        __builtin_amdgcn_s_setprio(1);
        acc[0][0] = __builtin_amdgcn_mfma_f32_32x32x16_bf16(af0[2], bg0[2], acc[0][0], 0, 0, 0);
        acc[0][1] = __builtin_amdgcn_mfma_f32_32x32x16_bf16(af0[2], bg1[2], acc[0][1], 0, 0, 0);
        acc[1][0] = __builtin_amdgcn_mfma_f32_32x32x16_bf16(af1[2], bg0[2], acc[1][0], 0, 0, 0);
        acc[1][1] = __builtin_amdgcn_mfma_f32_32x32x16_bf16(af1[2], bg1[2], acc[1][1], 0, 0, 0);
        acc[0][0] = __builtin_amdgcn_mfma_f32_32x32x16_bf16(af0[3], bg0[3], acc[0][0], 0, 0, 0);
        acc[0][1] = __builtin_amdgcn_mfma_f32_32x32x16_bf16(af0[3], bg1[3], acc[0][1], 0, 0, 0);
        acc[1][0] = __builtin_amdgcn_mfma_f32_32x32x16_bf16(af1[3], bg0[3], acc[1][0], 0, 0, 0);
        acc[1][1] = __builtin_amdgcn_mfma_f32_32x32x16_bf16(af1[3], bg1[3], acc[1][1], 0, 0, 0);
        __builtin_amdgcn_s_setprio(0);
    }

    // epilogue: D col=lane&31, row=(reg&3)+8*(reg>>2)+4*hi  (measured m74/m101)
    #pragma unroll
    for (int j = 0; j < 2; ++j) {
        const int c = col0 + wc * 64 + j * 32 + cl;
        const float bj = bias ? bias[c] : 0.f;
        float s = 0.f, s2 = 0.f;
        #pragma unroll
        for (int i = 0; i < 2; ++i) {
            #pragma unroll
            for (int reg = 0; reg < 16; ++reg) {
                const int rl = (reg & 3) + 8 * (reg >> 2) + 4 * hi;
                const int r = row0 + wr * 64 + i * 32 + rl;
                float x = acc[i][j][reg] + bj;
                x = x > 0.f ? x : 0.f;
                s += x; s2 += x * x;
                H[(size_t)r * N + c] = f2bf(x);
            }
        }
        s  += __shfl_xor(s, 32, 64);
        s2 += __shfl_xor(s2, 32, 64);
        if (hi == 0) {
            const int p = mm * 2 + wr;
            partS [(size_t)p * 1024 + c] = s;
            partS2[(size_t)p * 1024 + c] = s2;
        }
    }
}

// ---------------- BN finalize ----------------

__global__ __launch_bounds__(256) void bn_finalize(
    const float* __restrict__ partS, const float* __restrict__ partS2,
    const float* __restrict__ gamma, const float* __restrict__ beta,
    float* __restrict__ ss)
{
    int c = blockIdx.x * 256 + threadIdx.x;
    float s = 0.f, s2 = 0.f;
    for (int i = 0; i < 128; ++i) {
        s  += partS [(size_t)i * 1024 + c];
        s2 += partS2[(size_t)i * 1024 + c];
    }
    float mean = s * (1.0f / 8192.0f);
    float var  = fmaxf(s2 * (1.0f / 8192.0f) - mean * mean, 0.f);
    float sc   = gamma[c] * rsqrtf(var + 1e-5f);
    ss[c]        = sc;
    ss[1024 + c] = beta[c] - mean * sc;
}

// ---------------- head: out[8192,10] = BN3(H) @ W4T (K=1024) ----------------

__global__ __launch_bounds__(256) void head_kernel(
    const u16* __restrict__ H, const u16* __restrict__ W4T,
    const float* __restrict__ ss, float* __restrict__ out)
{
    const int lane = threadIdx.x & 63;
    const int wid  = threadIdx.x >> 6;
    const int r    = blockIdx.x * 4 + wid;

    float acc[10];
    #pragma unroll
    for (int c = 0; c < 10; c++) acc[c] = 0.f;

    #pragma unroll
    for (int j = 0; j < 16; ++j) {
        int k = j * 64 + lane;
        float a = fmaf(bf2f(H[(size_t)r * 1024 + k]), ss[k], ss[1024 + k]);
        ushort8 w0 = *(const ushort8*)(W4T + (size_t)k * 16);
        acc[0] += a * bf2f(w0[0]); acc[1] += a * bf2f(w0[1]);
        acc[2] += a * bf2f(w0[2]); acc[3] += a * bf2f(w0[3]);
        acc[4] += a * bf2f(w0[4]); acc[5] += a * bf2f(w0[5]);
        acc[6] += a * bf2f(w0[6]); acc[7] += a * bf2f(w0[7]);
        u16 w8 = W4T[(size_t)k * 16 + 8];
        u16 w9 = W4T[(size_t)k * 16 + 9];
        acc[8] += a * bf2f(w8);    acc[9] += a * bf2f(w9);
    }
    #pragma unroll
    for (int c = 0; c < 10; c++) {
        float s = acc[c];
        #pragma unroll
        for (int off = 32; off > 0; off >>= 1) s += __shfl_xor(s, off, 64);
        acc[c] = s;
    }
    if (lane == 0) {
        #pragma unroll
        for (int c = 0; c < 10; c++) out[(size_t)r * 10 + c] = acc[c];
    }
}

// ---------------- launch ----------------

extern "C" void kernel_launch(void* const* d_in, const int* in_sizes, int n_in,
                              void* d_out, int out_size, void* d_ws, size_t ws_size,
                              hipStream_t stream) {
    const float* x  = (const float*)d_in[0];
    const float* W1 = (const float*)d_in[1];
    const float* W2 = (const float*)d_in[2];
    const float* W3 = (const float*)d_in[3];
    const float* W4 = (const float*)d_in[4];
    const float* g1 = (const float*)d_in[5];
    const float* b1 = (const float*)d_in[6];
    const float* g2 = (const float*)d_in[7];
    const float* b2 = (const float*)d_in[8];
    const float* g3 = (const float*)d_in[9];
    const float* b3 = (const float*)d_in[10];
    float* out = (float*)d_out;

    char* ws = (char*)d_ws;
    u16*   Xb     = (u16*)  (ws + 0);           // 50,331,648 (x bf16)
    u16*   Hb0    = (u16*)  (ws + 50331648);    // 16,777,216
    u16*   Hb1    = (u16*)  (ws + 67108864);    // 16,777,216
    u16*   W1b    = (u16*)  (ws + 83886080);    //  6,291,456
    u16*   W2p    = (u16*)  (ws + 90177536);    //  2,097,152
    u16*   W3p    = (u16*)  (ws + 92274688);    //  2,097,152
    u16*   W4T    = (u16*)  (ws + 94371840);    //     32,768
    float* partS  = (float*)(ws + 94404608);    //    524,288
    float* partS2 = (float*)(ws + 94928896);    //    524,288
    float* ss     = (float*)(ws + 95453184);    //      8,192
    float* bias2  = (float*)(ws + 95461376);    //      4,096
    float* bias3  = (float*)(ws + 95465472);    //      4,096

    pre_kernel<<<13888, 256, 0, stream>>>(x, W1, W4, Xb, W1b, W4T);

    dim3 gemm_grid(64, 8);   // M/128, N/128

    // layer 1 (bf16 x, no bias)
    gemm_fused<<<gemm_grid, 256, 0, stream>>>(Xb, W1b, Hb0, nullptr, partS, partS2, 8192, 1024, 3072);
    bn_finalize<<<4, 256, 0, stream>>>(partS, partS2, g1, b1, ss);
    rescale_w<<<256, 256, 0, stream>>>(W2, ss, W2p, bias2);

    // layer 2
    gemm_fused<<<gemm_grid, 256, 0, stream>>>(Hb0, W2p, Hb1, bias2, partS, partS2, 8192, 1024, 1024);
    bn_finalize<<<4, 256, 0, stream>>>(partS, partS2, g2, b2, ss);
    rescale_w<<<256, 256, 0, stream>>>(W3, ss, W3p, bias3);

    // layer 3
    gemm_fused<<<gemm_grid, 256, 0, stream>>>(Hb1, W3p, Hb0, bias3, partS, partS2, 8192, 1024, 1024);
    bn_finalize<<<4, 256, 0, stream>>>(partS, partS2, g3, b3, ss);

    // head (BN3 applied on the fly)
    head_kernel<<<2048, 256, 0, stream>>>(Hb0, W4T, ss, out);
}